// Round 1
// baseline (380.068 us; speedup 1.0000x reference)
//
#include <hip/hip_runtime.h>

// SGC-Res: h = LayerNorm( (A @ feat) @ W^T + b )
// Pipeline per call:
//   1. memset counts
//   2. k_hist:    counts[row[e]]++            (int atomics, L2-resident)
//   3. k_scan1:   block-local exclusive scan of counts (1024/block)
//   4. k_scanb:   scan of block sums (single block)
//   5. k_addback: offs[i] += blockOffs[b]
//   6. k_scatter: CSR scatter (ecol, eval), advancing offs -> offs[i]=end_i
//   7. k_node:    per-node wave: gather-SpMM + 64x64 matvec + LayerNorm

__global__ __launch_bounds__(256) void k_hist(const int* __restrict__ row,
                                              int* __restrict__ counts, int E) {
    int t = blockIdx.x * 256 + threadIdx.x;
    if (t < E) atomicAdd(&counts[row[t]], 1);
}

__global__ __launch_bounds__(256) void k_scan1(const int* __restrict__ counts,
                                               int* __restrict__ offs,
                                               int* __restrict__ bsums) {
    int tid = threadIdx.x;
    int lane = tid & 63, wid = tid >> 6;
    int base = blockIdx.x * 1024 + tid * 4;
    int4 v = *reinterpret_cast<const int4*>(&counts[base]);
    int t0 = v.x, t01 = v.x + v.y, t012 = t01 + v.z, tt = t012 + v.w;
    int incl = tt;
#pragma unroll
    for (int o = 1; o < 64; o <<= 1) {
        int u = __shfl_up(incl, o);
        if (lane >= o) incl += u;
    }
    __shared__ int wsum[4];
    if (lane == 63) wsum[wid] = incl;
    __syncthreads();
    int woff = 0;
    for (int w = 0; w < wid; ++w) woff += wsum[w];
    int p = woff + incl - tt;  // block-local exclusive prefix
    offs[base + 0] = p;
    offs[base + 1] = p + t0;
    offs[base + 2] = p + t01;
    offs[base + 3] = p + t012;
    if (tid == 255) bsums[blockIdx.x] = woff + incl;  // block total
}

__global__ __launch_bounds__(256) void k_scanb(const int* __restrict__ bsums,
                                               int* __restrict__ boffs, int nb) {
    int tid = threadIdx.x, lane = tid & 63, wid = tid >> 6;
    int v = (tid < nb) ? bsums[tid] : 0;
    int incl = v;
#pragma unroll
    for (int o = 1; o < 64; o <<= 1) {
        int u = __shfl_up(incl, o);
        if (lane >= o) incl += u;
    }
    __shared__ int wsum[4];
    if (lane == 63) wsum[wid] = incl;
    __syncthreads();
    int woff = 0;
    for (int w = 0; w < wid; ++w) woff += wsum[w];
    if (tid < nb) boffs[tid] = woff + incl - v;  // exclusive
}

__global__ __launch_bounds__(256) void k_addback(int* __restrict__ offs,
                                                 const int* __restrict__ boffs) {
    int base = blockIdx.x * 1024 + threadIdx.x * 4;
    int add = boffs[blockIdx.x];
    int4 v = *reinterpret_cast<int4*>(&offs[base]);
    v.x += add; v.y += add; v.z += add; v.w += add;
    *reinterpret_cast<int4*>(&offs[base]) = v;
}

__global__ __launch_bounds__(256) void k_scatter(const int* __restrict__ row,
                                                 const int* __restrict__ col,
                                                 const float* __restrict__ vals,
                                                 int* __restrict__ offs,
                                                 int* __restrict__ ecol,
                                                 float* __restrict__ evals, int E) {
    int t = blockIdx.x * 256 + threadIdx.x;
    if (t >= E) return;
    int r = row[t];
    int p = atomicAdd(&offs[r], 1);   // offs[i] ends at end_i
    ecol[p] = col[t];
    evals[p] = vals[t];
}

// One 64-lane wave per node. lane = feature dim d (then = class c).
__global__ __launch_bounds__(256) void k_node(
    const float* __restrict__ feat, const int* __restrict__ ecol,
    const float* __restrict__ evals, const int* __restrict__ offs,
    const float* __restrict__ W, const float* __restrict__ bias,
    const float* __restrict__ gamma, const float* __restrict__ beta,
    float* __restrict__ out, int N)
{
    // W staged as wt[(d>>2)*256 + c*4 + (d&3)] = W[c*64+d]  -> float4 per (c, d4)
    __shared__ float wt[4096];
    for (int idx = threadIdx.x; idx < 4096; idx += 256) {
        int c = idx >> 6, d = idx & 63;
        wt[(d >> 2) * 256 + c * 4 + (d & 3)] = W[idx];
    }
    __syncthreads();

    int lane = threadIdx.x & 63;
    int n = (blockIdx.x * 256 + threadIdx.x) >> 6;
    if (n >= N) return;

    int end = offs[n];
    int start = (n == 0) ? 0 : offs[n - 1];

    // SpMM gather: acc = h[n][lane]
    float acc = 0.f;
    for (int b0 = start; b0 < end; b0 += 64) {
        int m = end - b0; if (m > 64) m = 64;
        int myc = 0; float myv = 0.f;
        if (lane < m) { myc = ecol[b0 + lane]; myv = evals[b0 + lane]; }
        for (int j = 0; j < m; ++j) {
            int   cc = __shfl(myc, j);
            float vv = __shfl(myv, j);
            acc += vv * feat[cc * 64 + lane];   // coalesced 256B per wave
        }
    }

    // Linear: o[c=lane] = b[c] + sum_d h[d] * W[c,d]
    float o = bias[lane];
#pragma unroll
    for (int d4 = 0; d4 < 16; ++d4) {
        float4 w4 = *reinterpret_cast<const float4*>(&wt[d4 * 256 + lane * 4]);
        o += __shfl(acc, 4 * d4 + 0) * w4.x;
        o += __shfl(acc, 4 * d4 + 1) * w4.y;
        o += __shfl(acc, 4 * d4 + 2) * w4.z;
        o += __shfl(acc, 4 * d4 + 3) * w4.w;
    }

    // LayerNorm over 64 lanes
    float s = o;
#pragma unroll
    for (int off = 32; off; off >>= 1) s += __shfl_xor(s, off);
    float mu = s * 0.015625f;
    float dv = o - mu;
    float vs = dv * dv;
#pragma unroll
    for (int off = 32; off; off >>= 1) vs += __shfl_xor(vs, off);
    float inv = rsqrtf(vs * 0.015625f + 1e-5f);
    out[n * 64 + lane] = dv * inv * gamma[lane] + beta[lane];
}

extern "C" void kernel_launch(void* const* d_in, const int* in_sizes, int n_in,
                              void* d_out, int out_size, void* d_ws, size_t ws_size,
                              hipStream_t stream) {
    const float* feat  = (const float*)d_in[0];
    // d_in[1] = feat_ori: dead code in reference, unused
    const int*   row   = (const int*)d_in[2];
    const int*   col   = (const int*)d_in[3];
    const float* vals  = (const float*)d_in[4];
    const float* W     = (const float*)d_in[5];
    const float* bias  = (const float*)d_in[6];
    const float* gamma = (const float*)d_in[7];
    const float* beta  = (const float*)d_in[8];
    float* out = (float*)d_out;

    const int D = 64;
    int N = in_sizes[0] / D;
    int E = in_sizes[2];

    int nb1 = (N + 1023) / 1024;      // scan blocks (98 for N=100000), <=256
    int NPAD = nb1 * 1024;

    char* ws = (char*)d_ws;
    int* counts = (int*)ws;                              // NPAD ints
    int* offs   = (int*)(ws + (size_t)NPAD * 4);         // NPAD ints
    int* bsums  = (int*)(ws + (size_t)NPAD * 8);         // <=1024 ints
    int* boffs  = bsums + 1024;                          // <=1024 ints
    size_t ebase = (size_t)NPAD * 8 + 8192;
    int*   ecol  = (int*)(ws + ebase);                   // E ints
    float* evals = (float*)(ws + ebase + (size_t)E * 4); // E floats

    hipMemsetAsync(counts, 0, (size_t)NPAD * 4, stream);
    k_hist   <<<(E + 255) / 256, 256, 0, stream>>>(row, counts, E);
    k_scan1  <<<nb1, 256, 0, stream>>>(counts, offs, bsums);
    k_scanb  <<<1, 256, 0, stream>>>(bsums, boffs, nb1);
    k_addback<<<nb1, 256, 0, stream>>>(offs, boffs);
    k_scatter<<<(E + 255) / 256, 256, 0, stream>>>(row, col, vals, offs, ecol, evals, E);
    k_node   <<<(N * 64 + 255) / 256, 256, 0, stream>>>(feat, ecol, evals, offs,
                                                        W, bias, gamma, beta, out, N);
}

// Round 2
// 314.639 us; speedup vs baseline: 1.2080x; 1.2080x over previous
//
#include <hip/hip_runtime.h>

// SGC-Res: out = LayerNorm( (A @ feat) @ W^T + b )
// Pipeline per call:
//   1. memset counts
//   2. k_hist:    counts[row[e]]++            (int atomics, L2-resident)
//   3. k_scan1:   block-local exclusive scan of counts (1024/block)
//   4. k_scanb:   scan of block sums (single block)
//   5. k_addback: offs[i] += blockOffs[b]
//   6. k_scatter: CSR scatter of packed (col,val) 8B pairs; offs[i] -> end_i
//   7. k_node:    per-node wave: gather-SpMM (8-deep ILP, uniform pair loads)
//                 + 64x64 matvec via LDS + LayerNorm

typedef unsigned int uint32;
typedef unsigned long long u64;

__global__ __launch_bounds__(256) void k_hist(const int* __restrict__ row,
                                              int* __restrict__ counts, int E) {
    int t = blockIdx.x * 256 + threadIdx.x;
    if (t < E) atomicAdd(&counts[row[t]], 1);
}

__global__ __launch_bounds__(256) void k_scan1(const int* __restrict__ counts,
                                               int* __restrict__ offs,
                                               int* __restrict__ bsums) {
    int tid = threadIdx.x;
    int lane = tid & 63, wid = tid >> 6;
    int base = blockIdx.x * 1024 + tid * 4;
    int4 v = *reinterpret_cast<const int4*>(&counts[base]);
    int t0 = v.x, t01 = v.x + v.y, t012 = t01 + v.z, tt = t012 + v.w;
    int incl = tt;
#pragma unroll
    for (int o = 1; o < 64; o <<= 1) {
        int u = __shfl_up(incl, o);
        if (lane >= o) incl += u;
    }
    __shared__ int wsum[4];
    if (lane == 63) wsum[wid] = incl;
    __syncthreads();
    int woff = 0;
    for (int w = 0; w < wid; ++w) woff += wsum[w];
    int p = woff + incl - tt;  // block-local exclusive prefix
    offs[base + 0] = p;
    offs[base + 1] = p + t0;
    offs[base + 2] = p + t01;
    offs[base + 3] = p + t012;
    if (tid == 255) bsums[blockIdx.x] = woff + incl;  // block total
}

__global__ __launch_bounds__(256) void k_scanb(const int* __restrict__ bsums,
                                               int* __restrict__ boffs, int nb) {
    int tid = threadIdx.x, lane = tid & 63, wid = tid >> 6;
    int v = (tid < nb) ? bsums[tid] : 0;
    int incl = v;
#pragma unroll
    for (int o = 1; o < 64; o <<= 1) {
        int u = __shfl_up(incl, o);
        if (lane >= o) incl += u;
    }
    __shared__ int wsum[4];
    if (lane == 63) wsum[wid] = incl;
    __syncthreads();
    int woff = 0;
    for (int w = 0; w < wid; ++w) woff += wsum[w];
    if (tid < nb) boffs[tid] = woff + incl - v;  // exclusive
}

__global__ __launch_bounds__(256) void k_addback(int* __restrict__ offs,
                                                 const int* __restrict__ boffs) {
    int base = blockIdx.x * 1024 + threadIdx.x * 4;
    int add = boffs[blockIdx.x];
    int4 v = *reinterpret_cast<int4*>(&offs[base]);
    v.x += add; v.y += add; v.z += add; v.w += add;
    *reinterpret_cast<int4*>(&offs[base]) = v;
}

__global__ __launch_bounds__(256) void k_scatter(const int* __restrict__ row,
                                                 const int* __restrict__ col,
                                                 const float* __restrict__ vals,
                                                 int* __restrict__ offs,
                                                 u64* __restrict__ epair, int E) {
    int t = blockIdx.x * 256 + threadIdx.x;
    if (t >= E) return;
    int r = row[t];
    int p = atomicAdd(&offs[r], 1);   // offs[i] ends at end_i
    u64 pk = (u64)(uint32)col[t] | ((u64)__float_as_uint(vals[t]) << 32);
    epair[p] = pk;                    // one 8B scatter instead of two 4B
}

// One 64-lane wave per node. lane = feature dim d (then = class c).
__global__ __launch_bounds__(256) void k_node(
    const float* __restrict__ feat, const u64* __restrict__ epair,
    const int* __restrict__ offs,
    const float* __restrict__ W, const float* __restrict__ bias,
    const float* __restrict__ gamma, const float* __restrict__ beta,
    float* __restrict__ out, int N)
{
    // W staged as wt[d4*256 + c*4 + j] = W[c*64 + d4*4 + j]
    __shared__ float wt[4096];
    __shared__ float hsh[256];
    for (int idx = threadIdx.x; idx < 4096; idx += 256) {
        int c = idx >> 6, d = idx & 63;
        wt[(d >> 2) * 256 + c * 4 + (d & 3)] = W[idx];
    }
    __syncthreads();

    int lane = threadIdx.x & 63;
    int wid = threadIdx.x >> 6;
    int n = blockIdx.x * 4 + wid;
    if (n >= N) return;

    int end = offs[n];
    int start = (n == 0) ? 0 : offs[n - 1];

    // SpMM gather: acc = h[n][lane]. 8 predicated edges per iteration:
    // all loads independent -> issued back-to-back before the waitcnt.
    float acc = 0.f;
    for (int b = start; b < end; b += 8) {
        int   cc[8];
        float vv[8];
#pragma unroll
        for (int k = 0; k < 8; ++k) {
            int idx = b + k;
            int cl = (idx < end) ? idx : (end - 1);   // clamp (valid addr)
            u64 pk = epair[cl];                        // uniform 8B broadcast
            cc[k] = (int)(uint32)pk;
            vv[k] = (idx < end) ? __uint_as_float((uint32)(pk >> 32)) : 0.f;
        }
        float f[8];
#pragma unroll
        for (int k = 0; k < 8; ++k)
            f[k] = feat[(size_t)cc[k] * 64 + lane];    // 8 coalesced 256B loads in flight
#pragma unroll
        for (int k = 0; k < 8; ++k)
            acc += vv[k] * f[k];
    }

    // Linear via LDS: lane c computes o = b[c] + sum_d h[d]*W[c,d]
    hsh[wid * 64 + lane] = acc;
    __syncthreads();   // cheap; guarantees hsh visible (same wave produces it)
    float o = bias[lane];
#pragma unroll
    for (int d4 = 0; d4 < 16; ++d4) {
        float4 h4 = *reinterpret_cast<const float4*>(&hsh[wid * 64 + d4 * 4]); // uniform bcast
        float4 w4 = *reinterpret_cast<const float4*>(&wt[d4 * 256 + lane * 4]);
        o += h4.x * w4.x + h4.y * w4.y + h4.z * w4.z + h4.w * w4.w;
    }

    // LayerNorm over 64 lanes
    float s = o;
#pragma unroll
    for (int off = 32; off; off >>= 1) s += __shfl_xor(s, off);
    float mu = s * 0.015625f;
    float dv = o - mu;
    float vs = dv * dv;
#pragma unroll
    for (int off = 32; off; off >>= 1) vs += __shfl_xor(vs, off);
    float inv = rsqrtf(vs * 0.015625f + 1e-5f);
    out[n * 64 + lane] = dv * inv * gamma[lane] + beta[lane];
}

extern "C" void kernel_launch(void* const* d_in, const int* in_sizes, int n_in,
                              void* d_out, int out_size, void* d_ws, size_t ws_size,
                              hipStream_t stream) {
    const float* feat  = (const float*)d_in[0];
    // d_in[1] = feat_ori: dead code in reference, unused
    const int*   row   = (const int*)d_in[2];
    const int*   col   = (const int*)d_in[3];
    const float* vals  = (const float*)d_in[4];
    const float* W     = (const float*)d_in[5];
    const float* bias  = (const float*)d_in[6];
    const float* gamma = (const float*)d_in[7];
    const float* beta  = (const float*)d_in[8];
    float* out = (float*)d_out;

    const int D = 64;
    int N = in_sizes[0] / D;
    int E = in_sizes[2];

    int nb1 = (N + 1023) / 1024;      // scan blocks (98 for N=100000), <=1024
    int NPAD = nb1 * 1024;

    char* ws = (char*)d_ws;
    int* counts = (int*)ws;                              // NPAD ints
    int* offs   = (int*)(ws + (size_t)NPAD * 4);         // NPAD ints
    int* bsums  = (int*)(ws + (size_t)NPAD * 8);         // <=1024 ints
    int* boffs  = bsums + 1024;                          // <=1024 ints
    size_t ebase = ((size_t)NPAD * 8 + 8192 + 15) & ~(size_t)15;
    u64*   epair = (u64*)(ws + ebase);                   // E pairs (8B)

    hipMemsetAsync(counts, 0, (size_t)NPAD * 4, stream);
    k_hist   <<<(E + 255) / 256, 256, 0, stream>>>(row, counts, E);
    k_scan1  <<<nb1, 256, 0, stream>>>(counts, offs, bsums);
    k_scanb  <<<1, 256, 0, stream>>>(bsums, boffs, nb1);
    k_addback<<<nb1, 256, 0, stream>>>(offs, boffs);
    k_scatter<<<(E + 255) / 256, 256, 0, stream>>>(row, col, vals, offs, epair, E);
    k_node   <<<(N + 3) / 4, 256, 0, stream>>>(feat, epair, offs,
                                               W, bias, gamma, beta, out, N);
}

// Round 3
// 308.421 us; speedup vs baseline: 1.2323x; 1.0202x over previous
//
#include <hip/hip_runtime.h>

// SGC-Res: out = LayerNorm( (A @ feat) @ W^T + b )
// Key identity: (A @ F) @ W^T = A @ (F @ W^T).  So:
//   k_gemm:  G = F @ W^T          (dense 100K x 64 x 64, W in VGPRs)
//   CSR build (hist/scan/scatter) of packed (col,val) 8B pairs
//   k_node:  per-node wave: h[c] = sum_e val_e * G[col_e][c]  (scalarized
//            edge loop: col/val in SGPRs, gather = load v,[s_base + lane])
//            then + bias, LayerNorm across the 64 lanes, store.

typedef unsigned int uint32;
typedef unsigned long long u64;

#define RFL(x) __builtin_amdgcn_readfirstlane(x)

__global__ __launch_bounds__(256) void k_hist(const int* __restrict__ row,
                                              int* __restrict__ counts, int E) {
    int base = (blockIdx.x * 256 + threadIdx.x) * 4;
    if (base + 4 <= E) {
        int4 r = *reinterpret_cast<const int4*>(&row[base]);
        atomicAdd(&counts[r.x], 1);
        atomicAdd(&counts[r.y], 1);
        atomicAdd(&counts[r.z], 1);
        atomicAdd(&counts[r.w], 1);
    } else {
        for (int i = base; i < E; ++i) atomicAdd(&counts[row[i]], 1);
    }
}

__global__ __launch_bounds__(256) void k_scan1(const int* __restrict__ counts,
                                               int* __restrict__ offs,
                                               int* __restrict__ bsums) {
    int tid = threadIdx.x;
    int lane = tid & 63, wid = tid >> 6;
    int base = blockIdx.x * 1024 + tid * 4;
    int4 v = *reinterpret_cast<const int4*>(&counts[base]);
    int t0 = v.x, t01 = v.x + v.y, t012 = t01 + v.z, tt = t012 + v.w;
    int incl = tt;
#pragma unroll
    for (int o = 1; o < 64; o <<= 1) {
        int u = __shfl_up(incl, o);
        if (lane >= o) incl += u;
    }
    __shared__ int wsum[4];
    if (lane == 63) wsum[wid] = incl;
    __syncthreads();
    int woff = 0;
    for (int w = 0; w < wid; ++w) woff += wsum[w];
    int p = woff + incl - tt;  // block-local exclusive prefix
    offs[base + 0] = p;
    offs[base + 1] = p + t0;
    offs[base + 2] = p + t01;
    offs[base + 3] = p + t012;
    if (tid == 255) bsums[blockIdx.x] = woff + incl;  // block total
}

__global__ __launch_bounds__(256) void k_scanb(const int* __restrict__ bsums,
                                               int* __restrict__ boffs, int nb) {
    int tid = threadIdx.x, lane = tid & 63, wid = tid >> 6;
    int v = (tid < nb) ? bsums[tid] : 0;
    int incl = v;
#pragma unroll
    for (int o = 1; o < 64; o <<= 1) {
        int u = __shfl_up(incl, o);
        if (lane >= o) incl += u;
    }
    __shared__ int wsum[4];
    if (lane == 63) wsum[wid] = incl;
    __syncthreads();
    int woff = 0;
    for (int w = 0; w < wid; ++w) woff += wsum[w];
    if (tid < nb) boffs[tid] = woff + incl - v;  // exclusive
}

__global__ __launch_bounds__(256) void k_addback(int* __restrict__ offs,
                                                 const int* __restrict__ boffs) {
    int base = blockIdx.x * 1024 + threadIdx.x * 4;
    int add = boffs[blockIdx.x];
    int4 v = *reinterpret_cast<int4*>(&offs[base]);
    v.x += add; v.y += add; v.z += add; v.w += add;
    *reinterpret_cast<int4*>(&offs[base]) = v;
}

__global__ __launch_bounds__(256) void k_scatter(const int* __restrict__ row,
                                                 const int* __restrict__ col,
                                                 const float* __restrict__ vals,
                                                 int* __restrict__ offs,
                                                 u64* __restrict__ epair, int E) {
    int base = (blockIdx.x * 256 + threadIdx.x) * 4;
    if (base + 4 <= E) {
        int4 r = *reinterpret_cast<const int4*>(&row[base]);
        int4 c = *reinterpret_cast<const int4*>(&col[base]);
        float4 v = *reinterpret_cast<const float4*>(&vals[base]);
        int p0 = atomicAdd(&offs[r.x], 1);
        int p1 = atomicAdd(&offs[r.y], 1);
        int p2 = atomicAdd(&offs[r.z], 1);
        int p3 = atomicAdd(&offs[r.w], 1);
        epair[p0] = (u64)(uint32)c.x | ((u64)__float_as_uint(v.x) << 32);
        epair[p1] = (u64)(uint32)c.y | ((u64)__float_as_uint(v.y) << 32);
        epair[p2] = (u64)(uint32)c.z | ((u64)__float_as_uint(v.z) << 32);
        epair[p3] = (u64)(uint32)c.w | ((u64)__float_as_uint(v.w) << 32);
    } else {
        for (int i = base; i < E; ++i) {
            int p = atomicAdd(&offs[row[i]], 1);
            epair[p] = (u64)(uint32)col[i] | ((u64)__float_as_uint(vals[i]) << 32);
        }
    }
}

// Dense G = F @ W^T. Block = 256 thr = 4 waves, 64 nodes/block.
// lane = output class c; W row held in 64 VGPRs; F broadcast from LDS.
__global__ __launch_bounds__(256) void k_gemm(const float* __restrict__ feat,
                                              const float* __restrict__ W,
                                              float* __restrict__ G, int N) {
    __shared__ float fs[4096];
    int lane = threadIdx.x & 63, wid = threadIdx.x >> 6;
    int n0 = blockIdx.x * 64;
    int valid = N - n0; if (valid > 64) valid = 64;
    int elems = valid * 64;
    for (int idx = threadIdx.x * 4; idx < elems; idx += 1024)
        *reinterpret_cast<float4*>(&fs[idx]) =
            *reinterpret_cast<const float4*>(&feat[(size_t)n0 * 64 + idx]);
    float wr[64];
#pragma unroll
    for (int d4 = 0; d4 < 16; ++d4) {
        float4 w4 = *reinterpret_cast<const float4*>(&W[lane * 64 + d4 * 4]);
        wr[d4 * 4 + 0] = w4.x; wr[d4 * 4 + 1] = w4.y;
        wr[d4 * 4 + 2] = w4.z; wr[d4 * 4 + 3] = w4.w;
    }
    __syncthreads();
    for (int j = 0; j < 16; ++j) {
        int r = wid * 16 + j;
        if (r >= valid) break;
        float o = 0.f;
#pragma unroll
        for (int d4 = 0; d4 < 16; ++d4) {
            float4 h4 = *reinterpret_cast<const float4*>(&fs[r * 64 + d4 * 4]); // uniform bcast
            o = fmaf(h4.x, wr[d4 * 4 + 0], o);
            o = fmaf(h4.y, wr[d4 * 4 + 1], o);
            o = fmaf(h4.z, wr[d4 * 4 + 2], o);
            o = fmaf(h4.w, wr[d4 * 4 + 3], o);
        }
        G[(size_t)(n0 + r) * 64 + lane] = o;
    }
}

// One 64-lane wave per node, lane = class c. No LDS, scalarized edge loop.
__global__ __launch_bounds__(256) void k_node(
    const float* __restrict__ G, const u64* __restrict__ epair,
    const int* __restrict__ offs, const float* __restrict__ bias,
    const float* __restrict__ gamma, const float* __restrict__ beta,
    float* __restrict__ out, int N)
{
    int lane = threadIdx.x & 63;
    int n = (blockIdx.x << 2) + (threadIdx.x >> 6);
    if (n >= N) return;
    int start = RFL((n == 0) ? 0 : offs[n - 1]);
    int end   = RFL(offs[n]);

    float acc0 = 0.f, acc1 = 0.f;
    int i = start;
    for (; i + 4 <= end; i += 4) {
        u64 p0 = epair[i], p1 = epair[i + 1], p2 = epair[i + 2], p3 = epair[i + 3];
        int c0 = RFL((int)(uint32)p0); uint32 b0 = RFL((uint32)(p0 >> 32));
        int c1 = RFL((int)(uint32)p1); uint32 b1 = RFL((uint32)(p1 >> 32));
        int c2 = RFL((int)(uint32)p2); uint32 b2 = RFL((uint32)(p2 >> 32));
        int c3 = RFL((int)(uint32)p3); uint32 b3 = RFL((uint32)(p3 >> 32));
        float f0 = G[((size_t)(uint32)c0 << 6) | lane];   // load v,[s_base+lane]
        float f1 = G[((size_t)(uint32)c1 << 6) | lane];
        float f2 = G[((size_t)(uint32)c2 << 6) | lane];
        float f3 = G[((size_t)(uint32)c3 << 6) | lane];
        acc0 = fmaf(__uint_as_float(b0), f0, acc0);
        acc1 = fmaf(__uint_as_float(b1), f1, acc1);
        acc0 = fmaf(__uint_as_float(b2), f2, acc0);
        acc1 = fmaf(__uint_as_float(b3), f3, acc1);
    }
    for (; i < end; ++i) {
        u64 p = epair[i];
        int c = RFL((int)(uint32)p); uint32 b = RFL((uint32)(p >> 32));
        acc0 = fmaf(__uint_as_float(b), G[((size_t)(uint32)c << 6) | lane], acc0);
    }
    float o = acc0 + acc1 + bias[lane];

    // LayerNorm over 64 lanes
    float s = o;
#pragma unroll
    for (int off = 32; off; off >>= 1) s += __shfl_xor(s, off);
    float mu = s * 0.015625f;
    float dv = o - mu;
    float vs = dv * dv;
#pragma unroll
    for (int off = 32; off; off >>= 1) vs += __shfl_xor(vs, off);
    float inv = rsqrtf(vs * 0.015625f + 1e-5f);
    out[((size_t)n << 6) + lane] = dv * inv * gamma[lane] + beta[lane];
}

// Fallback (ws too small for G): R2-style fused node kernel reading feat.
__global__ __launch_bounds__(256) void k_node_fb(
    const float* __restrict__ feat, const u64* __restrict__ epair,
    const int* __restrict__ offs,
    const float* __restrict__ W, const float* __restrict__ bias,
    const float* __restrict__ gamma, const float* __restrict__ beta,
    float* __restrict__ out, int N)
{
    __shared__ float wt[4096];
    __shared__ float hsh[256];
    for (int idx = threadIdx.x; idx < 4096; idx += 256) {
        int c = idx >> 6, d = idx & 63;
        wt[(d >> 2) * 256 + c * 4 + (d & 3)] = W[idx];
    }
    __syncthreads();
    int lane = threadIdx.x & 63;
    int wid = threadIdx.x >> 6;
    int n = blockIdx.x * 4 + wid;
    if (n >= N) return;
    int start = RFL((n == 0) ? 0 : offs[n - 1]);
    int end   = RFL(offs[n]);
    float acc = 0.f;
    for (int i = start; i < end; ++i) {
        u64 p = epair[i];
        int c = RFL((int)(uint32)p); uint32 b = RFL((uint32)(p >> 32));
        acc = fmaf(__uint_as_float(b), feat[((size_t)(uint32)c << 6) | lane], acc);
    }
    hsh[wid * 64 + lane] = acc;
    __syncthreads();
    float o = bias[lane];
#pragma unroll
    for (int d4 = 0; d4 < 16; ++d4) {
        float4 h4 = *reinterpret_cast<const float4*>(&hsh[wid * 64 + d4 * 4]);
        float4 w4 = *reinterpret_cast<const float4*>(&wt[d4 * 256 + lane * 4]);
        o += h4.x * w4.x + h4.y * w4.y + h4.z * w4.z + h4.w * w4.w;
    }
    float s = o;
#pragma unroll
    for (int off = 32; off; off >>= 1) s += __shfl_xor(s, off);
    float mu = s * 0.015625f;
    float dv = o - mu;
    float vs = dv * dv;
#pragma unroll
    for (int off = 32; off; off >>= 1) vs += __shfl_xor(vs, off);
    float inv = rsqrtf(vs * 0.015625f + 1e-5f);
    out[((size_t)n << 6) + lane] = dv * inv * gamma[lane] + beta[lane];
}

extern "C" void kernel_launch(void* const* d_in, const int* in_sizes, int n_in,
                              void* d_out, int out_size, void* d_ws, size_t ws_size,
                              hipStream_t stream) {
    const float* feat  = (const float*)d_in[0];
    // d_in[1] = feat_ori: dead code in reference, unused
    const int*   row   = (const int*)d_in[2];
    const int*   col   = (const int*)d_in[3];
    const float* vals  = (const float*)d_in[4];
    const float* W     = (const float*)d_in[5];
    const float* bias  = (const float*)d_in[6];
    const float* gamma = (const float*)d_in[7];
    const float* beta  = (const float*)d_in[8];
    float* out = (float*)d_out;

    const int D = 64;
    int N = in_sizes[0] / D;
    int E = in_sizes[2];

    int nb1 = (N + 1023) / 1024;
    int NPAD = nb1 * 1024;

    char* ws = (char*)d_ws;
    int* counts = (int*)ws;                              // NPAD ints
    int* offs   = (int*)(ws + (size_t)NPAD * 4);         // NPAD ints
    int* bsums  = (int*)(ws + (size_t)NPAD * 8);         // <=1024 ints
    // boffs = bsums + 1024
    int* boffs  = bsums + 1024;
    size_t ebase = ((size_t)NPAD * 8 + 8192 + 255) & ~(size_t)255;
    u64*   epair = (u64*)(ws + ebase);                   // E pairs (8B)
    size_t gbase = (ebase + (size_t)E * 8 + 255) & ~(size_t)255;
    float* G     = (float*)(ws + gbase);                 // N*64 floats
    size_t need  = gbase + (size_t)N * 64 * 4;

    hipMemsetAsync(counts, 0, (size_t)NPAD * 4, stream);
    int eb4 = (E / 4 + 255) / 256 + 1;   // covers tail
    k_hist   <<<eb4, 256, 0, stream>>>(row, counts, E);
    k_scan1  <<<nb1, 256, 0, stream>>>(counts, offs, bsums);
    k_scanb  <<<1, 256, 0, stream>>>(bsums, boffs, nb1);
    k_addback<<<nb1, 256, 0, stream>>>(offs, boffs);
    k_scatter<<<eb4, 256, 0, stream>>>(row, col, vals, offs, epair, E);

    if (ws_size >= need) {
        k_gemm <<<(N + 63) / 64, 256, 0, stream>>>(feat, W, G, N);
        k_node <<<(N + 3) / 4, 256, 0, stream>>>(G, epair, offs,
                                                 bias, gamma, beta, out, N);
    } else {
        k_node_fb<<<(N + 3) / 4, 256, 0, stream>>>(feat, epair, offs, W,
                                                   bias, gamma, beta, out, N);
    }
}